// Round 10
// baseline (148.191 us; speedup 1.0000x reference)
//
#include <hip/hip_runtime.h>

#define NV 40962
#define NK 9
#define CIN 32
#define COUT 32
#define NBS 4
#define VT 256                 // transpose v-tile
#define TP 260                 // transpose LDS row stride (dwords)
#define NT 2561                // v-tiles of 16 in main kernel
#define PGRID 256              // persistent blocks (1 per CU)
#define GROW 66                // Glds row stride, dwords (256B data + 8B pad)
#define NV81 (NV * 81)
#define NV9  (NV * 9)

typedef __attribute__((ext_vector_type(8))) short bf16x8;
typedef __attribute__((ext_vector_type(4))) float f32x4;

// round-to-nearest-even f32 -> bf16 pair packed in a dword (a=low, b=high)
__device__ __forceinline__ unsigned bf16pair(float a, float b) {
    unsigned ua = __float_as_uint(a), ub = __float_as_uint(b);
    ua = (ua + 0x7FFFu + ((ua >> 16) & 1u)) >> 16;
    ub = (ub + 0x7FFFu + ((ub >> 16) & 1u)) & 0xFFFF0000u;
    return (ua & 0xFFFFu) | ub;
}

// LDS-only barrier (no vmcnt drain): cross-wave data here moves via ds_write.
__device__ __forceinline__ void bar_lgkm() {
    asm volatile("s_waitcnt lgkmcnt(0)\n\ts_barrier" ::: "memory");
}

// async DMA: lane i copies 4B from g+4i -> lds_row+4i (wave-uniform LDS base)
__device__ __forceinline__ void dma_row4(const unsigned* g, unsigned* l) {
    __builtin_amdgcn_global_load_lds(
        (const __attribute__((address_space(1))) unsigned*)g,
        (__attribute__((address_space(3))) unsigned*)l, 4, 0, 0);
}

// ---------------------------------------------------------------------------
// Kernel 1: x [128 rows=(b*32+c)][V] f32 -> xt [v][b0|b1|b2|b3 x 32ch] bf16
// (256 B/row; one row serves all 4 batches of a gather).
// ---------------------------------------------------------------------------
__global__ void __launch_bounds__(256) transpose_x_bf16(
    const float* __restrict__ x, unsigned* __restrict__ xtw)
{
    __shared__ unsigned T[16 * TP];
    const int b  = blockIdx.x & 3;
    const int v0 = (blockIdx.x >> 2) * VT;
    const int t  = threadIdx.x;
    const int w  = t >> 6;
    const int L  = t & 63;
    const bool full = (v0 + VT <= NV);

    #pragma unroll
    for (int i = 0; i < 4; ++i) {
        const int q = w + 4 * i;             // ch-pair 0..15 (ch 2q, 2q+1)
        const float* rowA = x + (size_t)(b * 32 + 2 * q) * NV;
        const float* rowB = rowA + NV;
        #pragma unroll
        for (int h = 0; h < 2; ++h) {
            const int vl = 128 * h + 2 * L;
            float2 a, c;
            if (full) {
                a = *(const float2*)(rowA + v0 + vl);
                c = *(const float2*)(rowB + v0 + vl);
            } else {
                const int v = v0 + vl;
                a.x = (v     < NV) ? rowA[v]     : 0.0f;
                a.y = (v + 1 < NV) ? rowA[v + 1] : 0.0f;
                c.x = (v     < NV) ? rowB[v]     : 0.0f;
                c.y = (v + 1 < NV) ? rowB[v + 1] : 0.0f;
            }
            uint2 d;
            d.x = bf16pair(a.x, c.x);
            d.y = bf16pair(a.y, c.y);
            *(uint2*)&T[q * TP + vl] = d;
        }
    }
    __syncthreads();

    #pragma unroll
    for (int i = 0; i < 4; ++i) {
        const int vl = i * 64 + w * 16 + (L >> 2);
        const int u4 = L & 3;
        const int v  = v0 + vl;
        if (v < NV) {
            uint4 d;
            d.x = T[(4 * u4 + 0) * TP + vl];
            d.y = T[(4 * u4 + 1) * TP + vl];
            d.z = T[(4 * u4 + 2) * TP + vl];
            d.w = T[(4 * u4 + 3) * TP + vl];
            *(uint4*)&xtw[(size_t)v * 64 + b * 16 + 4 * u4] = d;
        }
    }
}

// itp global load for a 16-vertex tile (1296 dwords), per-element guarded.
__device__ __forceinline__ void load_itp(float itpv[3],
                                         const float* __restrict__ itp,
                                         int tile, int t)
{
    const size_t base = (size_t)tile * 1296;
    #pragma unroll
    for (int i = 0; i < 3; ++i) {
        const int o = i * 512 + t;
        itpv[i] = (o < 1296 && base + o < (size_t)NV81) ? itp[base + o] : 0.0f;
    }
}

// stage 1296 itp dwords into padded LDS [vl][k][12]
__device__ __forceinline__ void stage_itp(float* __restrict__ buf,
                                          const float itpv[3], int t)
{
    #pragma unroll
    for (int i = 0; i < 3; ++i) {
        const int o = i * 512 + t;
        if (o < 1296) {
            const int vl = o / 81;
            const int r  = o - vl * 81;
            const int kk = r / 9;
            const int jj = r - kk * 9;
            buf[vl * 108 + kk * 12 + jj] = itpv[i];
        }
    }
}

// idx global load for a tile (144 ints via threads t<144), guarded
__device__ __forceinline__ int load_idx(const int* __restrict__ index,
                                        int tile, int t)
{
    int r = 0;
    if (t < 144) {
        const size_t base = (size_t)tile * 144 + t;
        r = (base < (size_t)NV9) ? index[base] : 0;
    }
    return r;
}

// ---------------------------------------------------------------------------
// Kernel 2: persistent pipelined fused kernel, 512 thr (8 waves), 1 blk/CU.
// Gathers staged via global_load_lds row-DMA (1 inst = one 256B xt row) into
// double-buffered Glds -> TA line-lookups/tile drop 16x vs per-thread uint2
// gathers. W lives in registers (9 bf16x8 frags). Iter:
//   B: issue DMA(t+1)->Glds[g^1]; read Glds[g]+itp_s -> interp -> pack Alds;
//      nz ballots
//   E1 (lgkm-only) ; D: MFMA(W-regs x Alds) + mask + store; stage itp(t+1),
//   idx(t+2); issue t+2/t+3 loads ; E2 (__syncthreads: vmcnt drain = DMA done)
// ---------------------------------------------------------------------------
__global__ void __launch_bounds__(512) sparse_conv_mfma(
    const unsigned short* __restrict__ xt, const int* __restrict__ index,
    const float* __restrict__ itp, const float* __restrict__ w,
    const float* __restrict__ bias, float* __restrict__ out)
{
    __shared__ unsigned Glds[2][144 * GROW];       // 76032 B
    __shared__ unsigned short Alds[36 * 64 * 8];   // 36864 B
    __shared__ float itp_s[16 * 108];              //  6912 B
    __shared__ unsigned short idx_s[2][144];       //   576 B
    __shared__ unsigned long long nzb[8];          //    64 B

    const int t    = threadIdx.x;
    const int col  = t & 63;                 // b*16 + vloc (lane id)
    const int q    = t >> 6;                 // wave id
    const int b    = col >> 4;               // batch in B; K-quad in D
    const int vloc = col & 15;
    const unsigned* xtw = (const unsigned*)xt;

    // W fragments -> registers (once per block; L2-hot broadcast reads)
    bf16x8 wfr[9];
    {
        const int o = (q & 1) * 16 + vloc;   // D-phase output row
        const float* wo = w + o * 288 + b * 8;
        #pragma unroll
        for (int ks = 0; ks < 9; ++ks) {
            const float4 f0 = *(const float4*)(wo + ks * 32);
            const float4 f1 = *(const float4*)(wo + ks * 32 + 4);
            union { uint4 u; bf16x8 v; } cv;
            cv.u.x = bf16pair(f0.x, f0.y); cv.u.y = bf16pair(f0.z, f0.w);
            cv.u.z = bf16pair(f1.x, f1.y); cv.u.w = bf16pair(f1.z, f1.w);
            wfr[ks] = cv.v;
        }
    }

    // ---------------- prologue ----------------
    int tile = blockIdx.x;
    {
        const int i0 = load_idx(index, tile, t);
        const int i1 = load_idx(index, min(tile + PGRID, NT - 1), t);
        if (t < 144) { idx_s[0][t] = (unsigned short)i0;
                       idx_s[1][t] = (unsigned short)i1; }
    }
    float itpv[3];
    load_itp(itpv, itp, tile, t);
    stage_itp(itp_s, itpv, t);
    __syncthreads();                         // idx_s/itp_s visible

    // DMA gathers(t0) -> Glds[0]; wave q stages rows 18q..18q+17
    #pragma unroll
    for (int r = 0; r < 18; ++r) {
        const int row = q * 18 + r;
        const int nbr = idx_s[0][row];
        dma_row4(xtw + (size_t)nbr * 64 + col, &Glds[0][row * GROW]);
    }
    load_itp(itpv, itp, min(tile + PGRID, NT - 1), t);
    int idxn = load_idx(index, min(tile + 2 * PGRID, NT - 1), t);
    __syncthreads();                         // vmcnt drain: Glds[0] ready

    int g = 0, cur = 0;
    for (; tile < NT; tile += PGRID) {
        // ---- B: issue DMA(t+1) first (covered by B+D) ----
        #pragma unroll
        for (int r = 0; r < 18; ++r) {
            const int row = q * 18 + r;
            const int nbr = idx_s[cur ^ 1][row];
            dma_row4(xtw + (size_t)nbr * 64 + col, &Glds[g ^ 1][row * GROW]);
        }

        // consume Glds[g] + itp_s -> interp -> pack Alds
        unsigned nzbits = 0;
        float acc[4][NK];
        #pragma unroll
        for (int cc = 0; cc < 4; ++cc)
            #pragma unroll
            for (int j = 0; j < NK; ++j) acc[cc][j] = 0.0f;
        #pragma unroll
        for (int k = 0; k < NK; ++k) {
            const unsigned* p = &Glds[g][(vloc * 9 + k) * GROW + b * 16 + q * 2];
            const unsigned lo = p[0], hi = p[1];
            nzbits |= (lo | hi) & 0x7FFF7FFFu;
            const float g0 = __uint_as_float(lo << 16);
            const float g1 = __uint_as_float(lo & 0xFFFF0000u);
            const float g2 = __uint_as_float(hi << 16);
            const float g3 = __uint_as_float(hi & 0xFFFF0000u);
            const float4 ra = *(const float4*)&itp_s[vloc * 108 + k * 12];
            const float4 rb = *(const float4*)&itp_s[vloc * 108 + k * 12 + 4];
            const float  r8 = itp_s[vloc * 108 + k * 12 + 8];
            const float row[NK] = {ra.x, ra.y, ra.z, ra.w,
                                   rb.x, rb.y, rb.z, rb.w, r8};
            #pragma unroll
            for (int j = 0; j < NK; ++j) {
                acc[0][j] += g0 * row[j];
                acc[1][j] += g1 * row[j];
                acc[2][j] += g2 * row[j];
                acc[3][j] += g3 * row[j];
            }
        }
        // pack: thread's kdims 36q+4i2 .. +4 -> chunk (9q+i2)>>1, 8B half
        #pragma unroll
        for (int i2 = 0; i2 < 9; ++i2) {
            const int k0 = 4 * i2;
            const int chunk = (9 * q + i2) >> 1;
            const int off = 4 * ((q + i2) & 1);      // shorts
            uint2 d;
            d.x = bf16pair(acc[k0 / 9][k0 % 9],
                           acc[(k0 + 1) / 9][(k0 + 1) % 9]);
            d.y = bf16pair(acc[(k0 + 2) / 9][(k0 + 2) % 9],
                           acc[(k0 + 3) / 9][(k0 + 3) % 9]);
            *(uint2*)&Alds[(chunk * 64 + col) * 8 + off] = d;
        }
        const unsigned long long bal = __ballot(nzbits != 0);
        if (col == 0) nzb[q] = bal;

        bar_lgkm();                          // E1: Alds/nzb visible

        // ---- D: MFMA + store; pipeline maintenance ----
        {
            const int dq = b;                // K-quad
            const int bb = q >> 1;
            const int oh = q & 1;
            const int colw = bb * 16 + vloc;

            f32x4 a0 = {0.f, 0.f, 0.f, 0.f};
            #pragma unroll
            for (int ks = 0; ks < 9; ++ks) {
                const int ch = ks * 4 + dq;
                const bf16x8 bf = *(const bf16x8*)&Alds[(ch * 64 + colw) * 8];
                a0 = __builtin_amdgcn_mfma_f32_16x16x32_bf16(wfr[ks], bf, a0,
                                                             0, 0, 0);
            }

            const unsigned long long nz = nzb[0] | nzb[1] | nzb[2] | nzb[3] |
                                          nzb[4] | nzb[5] | nzb[6] | nzb[7];
            const float m = ((nz >> colw) & 1ull) ? 1.0f : 0.0f;
            const int vv = tile * 16 + vloc;
            if (vv < NV) {
                float* outb = out + (size_t)bb * (COUT * NV) + vv;
                #pragma unroll
                for (int r = 0; r < 4; ++r) {
                    const int o = oh * 16 + dq * 4 + r;
                    outb[(size_t)o * NV] = (a0[r] + bias[o]) * m;
                }
            }
        }
        stage_itp(itp_s, itpv, t);           // itp(t+1); safe after E1
        if (t < 144) idx_s[cur][t] = (unsigned short)idxn;   // idx(t+2)
        load_itp(itpv, itp, min(tile + 2 * PGRID, NT - 1), t);
        idxn = load_idx(index, min(tile + 3 * PGRID, NT - 1), t);

        __syncthreads();                     // E2: vmcnt drain -> DMA done
        g ^= 1; cur ^= 1;
    }
}

// ---------------------------------------------------------------------------
extern "C" void kernel_launch(void* const* d_in, const int* in_sizes, int n_in,
                              void* d_out, int out_size, void* d_ws, size_t ws_size,
                              hipStream_t stream)
{
    const float* x     = (const float*)d_in[0];
    const int*   index = (const int*)  d_in[1];
    const float* itp   = (const float*)d_in[2];
    const float* w     = (const float*)d_in[3];
    const float* bias  = (const float*)d_in[4];
    float*       out   = (float*)d_out;

    unsigned short* xt = (unsigned short*)d_ws;     // NV*256 B = 10.5 MB

    const int vtiles = (NV + VT - 1) / VT;   // 161
    hipLaunchKernelGGL(transpose_x_bf16, dim3(vtiles * NBS), dim3(256), 0,
                       stream, x, (unsigned*)xt);
    hipLaunchKernelGGL(sparse_conv_mfma, dim3(PGRID), dim3(512), 0,
                       stream, xt, index, itp, w, bias, out);
}

// Round 11
// 139.668 us; speedup vs baseline: 1.0610x; 1.0610x over previous
//
#include <hip/hip_runtime.h>
#include <hip/hip_bf16.h>

#define NV 40962
#define NK 9
#define CIN 32
#define COUT 32
#define NBS 4
#define VT 256                 // transpose v-tile
#define TP 260                 // transpose LDS row stride (dwords)
#define NT 2561                // v-tiles of 16 in main kernel
#define PGRID 512              // persistent blocks (2 per CU, all co-resident)
#define NV81 (NV * 81)
#define NV9  (NV * 9)

typedef __attribute__((ext_vector_type(8))) short bf16x8;
typedef __attribute__((ext_vector_type(4))) float f32x4;

// f32 pair -> packed bf16 dword (a=low), via v_cvt_pk_bf16_f32 (RNE)
__device__ __forceinline__ unsigned pkbf(float a, float b) {
    union { __hip_bfloat162 h2; unsigned u; } cv;
    cv.h2 = __float22bfloat162_rn(make_float2(a, b));
    return cv.u;
}

// LDS-only barrier (no vmcnt drain): cross-wave data here moves via ds_write;
// in-flight global loads are register-consumed by their issuing wave.
__device__ __forceinline__ void bar_lgkm() {
    asm volatile("s_waitcnt lgkmcnt(0)\n\ts_barrier" ::: "memory");
}

// ---------------------------------------------------------------------------
// Kernel 1: x [128 rows=(b*32+c)][V] f32 -> xt [v][b0|b1|b2|b3 x 32ch] bf16
// (256 B/row; one row serves all 4 batches of a gather).
// ---------------------------------------------------------------------------
__global__ void __launch_bounds__(256) transpose_x_bf16(
    const float* __restrict__ x, unsigned* __restrict__ xtw)
{
    __shared__ unsigned T[16 * TP];
    const int b  = blockIdx.x & 3;
    const int v0 = (blockIdx.x >> 2) * VT;
    const int t  = threadIdx.x;
    const int w  = t >> 6;
    const int L  = t & 63;
    const bool full = (v0 + VT <= NV);

    #pragma unroll
    for (int i = 0; i < 4; ++i) {
        const int q = w + 4 * i;             // ch-pair 0..15 (ch 2q, 2q+1)
        const float* rowA = x + (size_t)(b * 32 + 2 * q) * NV;
        const float* rowB = rowA + NV;
        #pragma unroll
        for (int h = 0; h < 2; ++h) {
            const int vl = 128 * h + 2 * L;
            float2 a, c;
            if (full) {
                a = *(const float2*)(rowA + v0 + vl);
                c = *(const float2*)(rowB + v0 + vl);
            } else {
                const int v = v0 + vl;
                a.x = (v     < NV) ? rowA[v]     : 0.0f;
                a.y = (v + 1 < NV) ? rowA[v + 1] : 0.0f;
                c.x = (v     < NV) ? rowB[v]     : 0.0f;
                c.y = (v + 1 < NV) ? rowB[v + 1] : 0.0f;
            }
            uint2 d;
            d.x = pkbf(a.x, c.x);
            d.y = pkbf(a.y, c.y);
            *(uint2*)&T[q * TP + vl] = d;
        }
    }
    __syncthreads();

    #pragma unroll
    for (int i = 0; i < 4; ++i) {
        const int vl = i * 64 + w * 16 + (L >> 2);
        const int u4 = L & 3;
        const int v  = v0 + vl;
        if (v < NV) {
            uint4 d;
            d.x = T[(4 * u4 + 0) * TP + vl];
            d.y = T[(4 * u4 + 1) * TP + vl];
            d.z = T[(4 * u4 + 2) * TP + vl];
            d.w = T[(4 * u4 + 3) * TP + vl];
            *(uint4*)&xtw[(size_t)v * 64 + b * 16 + 4 * u4] = d;
        }
    }
}

// itp global load for a 16-vertex tile (1296 dwords), per-element guarded.
__device__ __forceinline__ void load_itp(float itpv[3],
                                         const float* __restrict__ itp,
                                         int tile, int t)
{
    const size_t base = (size_t)tile * 1296;
    #pragma unroll
    for (int i = 0; i < 3; ++i) {
        const int o = i * 512 + t;
        itpv[i] = (o < 1296 && base + o < (size_t)NV81) ? itp[base + o] : 0.0f;
    }
}

// stage 1296 itp dwords into padded LDS [vl][k][12]
__device__ __forceinline__ void stage_itp(float* __restrict__ buf,
                                          const float itpv[3], int t)
{
    #pragma unroll
    for (int i = 0; i < 3; ++i) {
        const int o = i * 512 + t;
        if (o < 1296) {
            const int vl = o / 81;
            const int r  = o - vl * 81;
            const int kk = r / 9;
            const int jj = r - kk * 9;
            buf[vl * 108 + kk * 12 + jj] = itpv[i];
        }
    }
}

// idx global load for a tile (144 ints via threads t<144), guarded
__device__ __forceinline__ int load_idx(const int* __restrict__ index,
                                        int tile, int t)
{
    int r = 0;
    if (t < 144) {
        const size_t base = (size_t)tile * 144 + t;
        r = (base < (size_t)NV9) ? index[base] : 0;
    }
    return r;
}

// interp consume of one neighbor k: unpack 4ch bf16 + 36 FMA vs itp row
__device__ __forceinline__ void consume_k(const uint2 gk,
                                          const float* __restrict__ irow,
                                          float acc[4][NK], unsigned& nzbits)
{
    const unsigned lo = gk.x, hi = gk.y;
    nzbits |= (lo | hi) & 0x7FFF7FFFu;
    const float g0 = __uint_as_float(lo << 16);
    const float g1 = __uint_as_float(lo & 0xFFFF0000u);
    const float g2 = __uint_as_float(hi << 16);
    const float g3 = __uint_as_float(hi & 0xFFFF0000u);
    const float4 ra = *(const float4*)irow;
    const float4 rb = *(const float4*)(irow + 4);
    const float  rc = irow[8];
    const float row[NK] = {ra.x, ra.y, ra.z, ra.w, rb.x, rb.y, rb.z, rb.w, rc};
    #pragma unroll
    for (int j = 0; j < NK; ++j) {
        acc[0][j] += g0 * row[j];
        acc[1][j] += g1 * row[j];
        acc[2][j] += g2 * row[j];
        acc[3][j] += g3 * row[j];
    }
}

// ---------------------------------------------------------------------------
// Kernel 2: persistent pipelined fused kernel (r8 structure), 512 thr, 2/CU.
// Changes vs r8: v_cvt_pk_bf16_f32 packs; Alds as 8B planes [72][64][8B]
// (pack b64 writes 8-way -> 4-way, D-reads conflict-free b64 pairs);
// gathers for t+1 issued mid-B (k0-3) and post-B (k4-8) for wider cover.
// ---------------------------------------------------------------------------
__global__ void __launch_bounds__(512) sparse_conv_mfma(
    const unsigned short* __restrict__ xt, const int* __restrict__ index,
    const float* __restrict__ itp, const float* __restrict__ w,
    const float* __restrict__ bias, float* __restrict__ out)
{
    __shared__ unsigned Alds8[72 * 64 * 2];        // 36864 B: plane h holds k=4h..4h+3
    __shared__ unsigned short Wlds[36 * 32 * 8];   // 18432 B
    __shared__ float itp_s[16 * 108];              //  6912 B
    __shared__ int   idx_s[2][144];                //  1152 B
    __shared__ unsigned long long nzb[8];          //    64 B

    const int t    = threadIdx.x;
    const int col  = t & 63;                 // b*16 + vloc (lane id)
    const int q    = t >> 6;                 // wave id; ch-group c = 4q..4q+3
    const int b    = col >> 4;               // batch in B; K-quad in D
    const int vloc = col & 15;
    const unsigned short* gb = xt + b * 32 + q * 4;

    // ---------------- prologue ----------------
    int tile = blockIdx.x;

    // stage W: chunk ch holds W[o][ch*8 .. ch*8+8) as 16B per o
    #pragma unroll
    for (int r = 0; r < 3; ++r) {
        const int j = t + r * 512;
        if (j < 1152) {
            const int o = j & 31;
            const int c = j >> 5;
            const float4 f0 = *(const float4*)(w + o * 288 + c * 8);
            const float4 f1 = *(const float4*)(w + o * 288 + c * 8 + 4);
            uint4 d;
            d.x = pkbf(f0.x, f0.y); d.y = pkbf(f0.z, f0.w);
            d.z = pkbf(f1.x, f1.y); d.w = pkbf(f1.z, f1.w);
            *(uint4*)&Wlds[(c * 32 + o) * 8] = d;
        }
    }
    {
        const int i0 = load_idx(index, tile, t);
        const int i1 = load_idx(index, min(tile + PGRID, NT - 1), t);
        if (t < 144) { idx_s[0][t] = i0; idx_s[1][t] = i1; }
    }
    float itpv[3];
    load_itp(itpv, itp, tile, t);
    stage_itp(itp_s, itpv, t);
    __syncthreads();                         // Wlds/idx_s/itp_s visible

    uint2 gath[NK];
    #pragma unroll
    for (int k = 0; k < NK; ++k) {           // gathers(t0)
        const int nbr = idx_s[0][vloc * 9 + k];
        gath[k] = *(const uint2*)(gb + (size_t)nbr * 128);
    }
    load_itp(itpv, itp, min(tile + PGRID, NT - 1), t);
    int idxn = load_idx(index, min(tile + 2 * PGRID, NT - 1), t);
    int cur = 0;

    for (; tile < NT; tile += PGRID) {
        // ---- B: consume gath(t)+itp_s -> interp; interleave gath(t+1) issue
        unsigned nzbits = 0;
        float acc[4][NK];
        #pragma unroll
        for (int cc = 0; cc < 4; ++cc)
            #pragma unroll
            for (int j = 0; j < NK; ++j) acc[cc][j] = 0.0f;
        const float* ib = &itp_s[vloc * 108];

        #pragma unroll
        for (int k = 0; k < 4; ++k) consume_k(gath[k], ib + k * 12, acc, nzbits);
        #pragma unroll
        for (int k = 0; k < 4; ++k) {        // reissue k0-3 early: cover = rest of B+E1+D+E2
            const int nbr = idx_s[cur ^ 1][vloc * 9 + k];
            gath[k] = *(const uint2*)(gb + (size_t)nbr * 128);
        }
        #pragma unroll
        for (int k = 4; k < 9; ++k) consume_k(gath[k], ib + k * 12, acc, nzbits);
        #pragma unroll
        for (int k = 4; k < 9; ++k) {
            const int nbr = idx_s[cur ^ 1][vloc * 9 + k];
            gath[k] = *(const uint2*)(gb + (size_t)nbr * 128);
        }

        // pack: thread's k = 36q+4*i2 .. +4 -> plane h = 9q+i2 (8B per col)
        #pragma unroll
        for (int i2 = 0; i2 < 9; ++i2) {
            const int k0 = 4 * i2;
            const int h  = 9 * q + i2;
            uint2 d;
            d.x = pkbf(acc[k0 / 9][k0 % 9],
                       acc[(k0 + 1) / 9][(k0 + 1) % 9]);
            d.y = pkbf(acc[(k0 + 2) / 9][(k0 + 2) % 9],
                       acc[(k0 + 3) / 9][(k0 + 3) % 9]);
            *(uint2*)&Alds8[(h * 64 + col) * 2] = d;
        }
        const unsigned long long bal = __ballot(nzbits != 0);
        if (col == 0) nzb[q] = bal;

        bar_lgkm();                          // E1: Alds8/nzb visible

        // ---- D: MFMA + store; pipeline maintenance ----
        {
            const int dq = b;                // K-quad
            const int bb = q >> 1;
            const int oh = q & 1;
            const int colw = bb * 16 + vloc;

            f32x4 a0 = {0.f, 0.f, 0.f, 0.f};
            #pragma unroll
            for (int ks = 0; ks < 9; ++ks) {
                const int h0 = ks * 8 + dq * 2;
                const uint2 l2 = *(const uint2*)&Alds8[(h0 * 64 + colw) * 2];
                const uint2 h2 = *(const uint2*)&Alds8[((h0 + 1) * 64 + colw) * 2];
                union { uint4 u; bf16x8 v; } f;
                f.u.x = l2.x; f.u.y = l2.y; f.u.z = h2.x; f.u.w = h2.y;
                const int ch = ks * 4 + dq;
                const bf16x8 wa = *(const bf16x8*)&Wlds[(ch * 32 + oh * 16 + vloc) * 8];
                a0 = __builtin_amdgcn_mfma_f32_16x16x32_bf16(wa, f.v, a0, 0, 0, 0);
            }

            const unsigned long long nz = nzb[0] | nzb[1] | nzb[2] | nzb[3] |
                                          nzb[4] | nzb[5] | nzb[6] | nzb[7];
            const float m = ((nz >> colw) & 1ull) ? 1.0f : 0.0f;
            const int vv = tile * 16 + vloc;
            if (vv < NV) {
                float* outb = out + (size_t)bb * (COUT * NV) + vv;
                #pragma unroll
                for (int r = 0; r < 4; ++r) {
                    const int o = oh * 16 + dq * 4 + r;
                    outb[(size_t)o * NV] = (a0[r] + bias[o]) * m;
                }
            }
        }
        stage_itp(itp_s, itpv, t);           // itp(t+1); safe after E1
        if (t < 144) idx_s[cur][t] = idxn;   // idx(t+2)
        load_itp(itpv, itp, min(tile + 2 * PGRID, NT - 1), t);
        idxn = load_idx(index, min(tile + 3 * PGRID, NT - 1), t);

        bar_lgkm();                          // E2: Alds reads done before reuse
        cur ^= 1;
    }
}

// ---------------------------------------------------------------------------
extern "C" void kernel_launch(void* const* d_in, const int* in_sizes, int n_in,
                              void* d_out, int out_size, void* d_ws, size_t ws_size,
                              hipStream_t stream)
{
    const float* x     = (const float*)d_in[0];
    const int*   index = (const int*)  d_in[1];
    const float* itp   = (const float*)d_in[2];
    const float* w     = (const float*)d_in[3];
    const float* bias  = (const float*)d_in[4];
    float*       out   = (float*)d_out;

    unsigned short* xt = (unsigned short*)d_ws;     // NV*256 B = 10.5 MB

    const int vtiles = (NV + VT - 1) / VT;   // 161
    hipLaunchKernelGGL(transpose_x_bf16, dim3(vtiles * NBS), dim3(256), 0,
                       stream, x, (unsigned*)xt);
    hipLaunchKernelGGL(sparse_conv_mfma, dim3(PGRID), dim3(512), 0,
                       stream, xt, index, itp, w, bias, out);
}